// Round 5
// baseline (212.198 us; speedup 1.0000x reference)
//
#include <hip/hip_runtime.h>

typedef __attribute__((ext_vector_type(8))) short bf16x8;
typedef __attribute__((ext_vector_type(4))) float f32x4;
typedef unsigned short u16;
typedef unsigned int u32;

#define MFMA16(A, B, C) __builtin_amdgcn_mfma_f32_16x16x32_bf16((A), (B), (C), 0, 0, 0)

#if __has_builtin(__builtin_amdgcn_exp2f)
#define EXP2(x) __builtin_amdgcn_exp2f(x)
#else
#define EXP2(x) exp2f(x)
#endif

typedef __attribute__((address_space(3))) unsigned int lds_u32;
typedef const __attribute__((address_space(1))) unsigned int glb_u32;

__device__ __forceinline__ u16 f2bf(float f) {
  union { float f; unsigned u; } x; x.f = f;
  unsigned r = (x.u + 0x7fffu + ((x.u >> 16) & 1u)) >> 16;
  return (u16)r;
}
__device__ __forceinline__ float bf2f(u16 h) {
  union { float f; unsigned u; } x; x.u = ((unsigned)h) << 16;
  return x.f;
}

// stage a 64x64 bf16 tile (ld=64) into contiguous LDS via global_load_lds,
// XOR-swizzled: LDS slot (row, c) holds global chunk c^(row&7).
__device__ __forceinline__ void stage_sw64(const u16* src, u16* lds, int tid) {
#pragma unroll
  for (int i = 0; i < 2; i++) {
    int vv = tid + i * 256;
    int row = vv >> 3, c = vv & 7;
    const u16* gp = src + (size_t)row * 64 + (size_t)(c ^ (row & 7)) * 8;
    __builtin_amdgcn_global_load_lds((glb_u32*)gp,
        (lds_u32*)(lds + (size_t)(i * 256 + (tid & 192)) * 8), 16, 0, 0);
  }
}

// stage ROWS x 64 bf16 tile from a row-major [*][512] matrix (ld=512) into
// contiguous LDS, same XOR swizzle. ROWS in {64, 128}.
template <int ROWS>
__device__ __forceinline__ void stage_ld512(const u16* src, u16* lds, int tid) {
#pragma unroll
  for (int i = 0; i < ROWS / 32; i++) {
    int vv = tid + i * 256;
    int row = vv >> 3, c = vv & 7;
    const u16* gp = src + (size_t)row * 512 + (size_t)(c ^ (row & 7)) * 8;
    __builtin_amdgcn_global_load_lds((glb_u32*)gp,
        (lds_u32*)(lds + (size_t)(i * 256 + (tid & 192)) * 8), 16, 0, 0);
  }
}

// ---------------- fused prep kernel ----------------
// blocks [0,4096): cast x -> xb (bf16)
// blocks [4096,4288): W_attn [512][1536] -> wta [1536][512] bf16 (64x64 tiles)
// blocks [4288,4352): W_out [512][512] -> whi/wlo [512][512] bf16 (hi/lo split)
// Branches are block-uniform; barriers only inside the transpose paths.
__global__ __launch_bounds__(256) void prep_kernel(const float* __restrict__ x,
                                                   u16* __restrict__ xb,
                                                   const float* __restrict__ Wa,
                                                   u16* __restrict__ wta,
                                                   const float* __restrict__ Wo,
                                                   u16* __restrict__ whi,
                                                   u16* __restrict__ wlo) {
  __shared__ u16 Th[64][72];
  __shared__ u16 Tl[64][72];
  const int bid = blockIdx.x;
  const int tid = threadIdx.x;

  if (bid < 4096) {
    // cast_x: 4096*256 == 4*2048*512/4 exactly, no bounds check needed
    int i = bid * 256 + tid;
    float4 v = ((const float4*)x)[i];
    ushort4 o;
    o.x = f2bf(v.x); o.y = f2bf(v.y); o.z = f2bf(v.z); o.w = f2bf(v.w);
    ((ushort4*)xb)[i] = o;
    return;
  }

  if (bid < 4288) {
    // trans_wa: t in [0,192): n-tile = t%24, k-tile = t/24
    const int t = bid - 4096;
    const int n0 = (t % 24) * 64;
    const int k0 = (t / 24) * 64;
    const int r = tid >> 4, c4 = (tid & 15) * 4;
#pragma unroll
    for (int i = 0; i < 4; i++) {
      int row = r + i * 16;
      float4 v = *(const float4*)&Wa[(size_t)(k0 + row) * 1536 + n0 + c4];
      Th[c4 + 0][row] = f2bf(v.x);
      Th[c4 + 1][row] = f2bf(v.y);
      Th[c4 + 2][row] = f2bf(v.z);
      Th[c4 + 3][row] = f2bf(v.w);
    }
    __syncthreads();
    const int row = tid >> 2, c16 = (tid & 3) * 16;
    *(uint4*)&wta[(size_t)(n0 + row) * 512 + k0 + c16]     = *(uint4*)&Th[row][c16];
    *(uint4*)&wta[(size_t)(n0 + row) * 512 + k0 + c16 + 8] = *(uint4*)&Th[row][c16 + 8];
    return;
  }

  {
    // trans_wo: t in [0,64): n-tile = t%8, k-tile = t/8
    const int t = bid - 4288;
    const int n0 = (t & 7) * 64;
    const int k0 = (t >> 3) * 64;
    const int r = tid >> 4, c4 = (tid & 15) * 4;
#pragma unroll
    for (int i = 0; i < 4; i++) {
      int row = r + i * 16;
      float4 v = *(const float4*)&Wo[(size_t)(k0 + row) * 512 + n0 + c4];
      float vv[4] = {v.x, v.y, v.z, v.w};
#pragma unroll
      for (int jj = 0; jj < 4; jj++) {
        u16 hi = f2bf(vv[jj]);
        Th[c4 + jj][row] = hi;
        Tl[c4 + jj][row] = f2bf(vv[jj] - bf2f(hi));
      }
    }
    __syncthreads();
    const int row = tid >> 2, c16 = (tid & 3) * 16;
    *(uint4*)&whi[(size_t)(n0 + row) * 512 + k0 + c16]     = *(uint4*)&Th[row][c16];
    *(uint4*)&whi[(size_t)(n0 + row) * 512 + k0 + c16 + 8] = *(uint4*)&Th[row][c16 + 8];
    *(uint4*)&wlo[(size_t)(n0 + row) * 512 + k0 + c16]     = *(uint4*)&Tl[row][c16];
    *(uint4*)&wlo[(size_t)(n0 + row) * 512 + k0 + c16 + 8] = *(uint4*)&Tl[row][c16 + 8];
  }
}

// ---------------- QKV GEMM (128x128 tile, m97 structure, XCD-banded) -----
// 768 blocks, 3/CU. LDS 32 KB single-buffer; global_load_lds staging with
// XOR swizzle; 2 barriers per K-step; 4x4 frag acc per wave (64x64/wave).
// Q: scaled by 0.125*log2(e), [bh][t][64]
// K: [bh][t][64]
// V: frag-packed V'[bh][it][ks][d][quad][jj]
__global__ __launch_bounds__(256) void gemm_qkv(const u16* __restrict__ xb,
                                                const u16* __restrict__ wta,
                                                const float* __restrict__ b_attn,
                                                u16* __restrict__ q,
                                                u16* __restrict__ kk,
                                                u16* __restrict__ v) {
  __shared__ u16 A_lds[128 * 64];
  __shared__ u16 B_lds[128 * 64];
  // XCD banding: each XCD owns an 8-m-tile stripe (1 MB A) -> L2-resident
  const int bid = blockIdx.x;
  const int xcd = bid & 7, rr = bid >> 3;       // rr in [0,96)
  const int m0 = (xcd * 8 + (rr & 7)) * 128;    // 64 m-tiles
  const int n0 = (rr >> 3) * 128;               // 12 n-tiles
  const int tid  = threadIdx.x;
  const int lane = tid & 63, w = tid >> 6;
  const int wm = w >> 1, wn = w & 1;
  const int quad = lane >> 4, l15 = lane & 15;
  const int sw0 = ((quad)     ^ (l15 & 7)) * 8;
  const int sw1 = ((quad + 4) ^ (l15 & 7)) * 8;

  f32x4 acc[4][4] = {};

  for (int kt = 0; kt < 8; kt++) {
    stage_ld512<128>(xb  + (size_t)m0 * 512 + kt * 64, A_lds, tid);
    stage_ld512<128>(wta + (size_t)n0 * 512 + kt * 64, B_lds, tid);
    __syncthreads();
#pragma unroll
    for (int ks = 0; ks < 2; ks++) {
      const int sw = ks ? sw1 : sw0;
      bf16x8 af[4], bf[4];
#pragma unroll
      for (int ri = 0; ri < 4; ri++)
        af[ri] = *(const bf16x8*)&A_lds[(wm * 64 + ri * 16 + l15) * 64 + sw];
#pragma unroll
      for (int ci = 0; ci < 4; ci++)
        bf[ci] = *(const bf16x8*)&B_lds[(wn * 64 + ci * 16 + l15) * 64 + sw];
#pragma unroll
      for (int ri = 0; ri < 4; ri++)
#pragma unroll
        for (int ci = 0; ci < 4; ci++)
          acc[ri][ci] = MFMA16(af[ri], bf[ci], acc[ri][ci]);
    }
    __syncthreads();
  }

  const float QS = 0.18033688011112043f;  // 0.125 * log2(e)
#pragma unroll
  for (int ri = 0; ri < 4; ri++) {
#pragma unroll
    for (int ci = 0; ci < 4; ci++) {
      int n = n0 + wn * 64 + ci * 16 + l15;
      float bias = b_attn[n];
      int chunk = n >> 9;
      int c = n & 511;
      int h = c >> 6, d = c & 63;
      int m_base = m0 + wm * 64 + ri * 16 + quad * 4;
      int b = m_base >> 11, t0 = m_base & 2047;
      int bh = b * 8 + h;
      if (chunk == 0) {
#pragma unroll
        for (int r = 0; r < 4; r++)
          q[(size_t)(bh * 2048 + t0 + r) * 64 + d] = f2bf((acc[ri][ci][r] + bias) * QS);
      } else if (chunk == 1) {
#pragma unroll
        for (int r = 0; r < 4; r++)
          kk[(size_t)(bh * 2048 + t0 + r) * 64 + d] = f2bf(acc[ri][ci][r] + bias);
      } else {
        int it = t0 >> 7, ks2 = (t0 >> 5) & 3, qd = (t0 >> 3) & 3, jj = t0 & 7;
        ushort4 pk;
        pk.x = f2bf(acc[ri][ci][0] + bias);
        pk.y = f2bf(acc[ri][ci][1] + bias);
        pk.z = f2bf(acc[ri][ci][2] + bias);
        pk.w = f2bf(acc[ri][ci][3] + bias);
        size_t idx = ((((size_t)bh * 16 + it) * 4 + ks2) * 64 + d) * 32 + qd * 8 + jj;
        *(ushort4*)&v[idx] = pk;
      }
    }
  }
}

// ---------------- flash attention ----------------
// r1 structure + 2-tile S/PV pipeline (r3). This round: split into two
// half-grid launches (ybase 0/32) purely for rocprof visibility — drops the
// top-5 duration threshold to ~41 us so the GEMMs surface if they are the
// hidden cost. Blocks are independent; split is correctness-neutral.
__global__ __launch_bounds__(256, 4) void flash_attn(const u16* __restrict__ q,
                                                     const u16* __restrict__ k,
                                                     const u16* __restrict__ vt,
                                                     u16* __restrict__ yb,
                                                     int ybase) {
  __shared__ u16 K_lds[2][64 * 64];
  __shared__ u16 P_lds[4 * 2 * 16 * 72];  // per-wave 2 x [16 q][64 +pad]

  const int flat = (blockIdx.y + ybase) * 16 + blockIdx.x;
  const int bh = (flat & 7) * 4 + ((flat >> 3) & 3);  // 4 bh per XCD -> K/V L2-resident
  const int qt = flat >> 5;                           // 0..31, 64 q-rows each

  const int tid  = threadIdx.x;
  const int lane = tid & 63, w = tid >> 6;
  const int quad = lane >> 4, l15 = lane & 15;
  const int sw0 = ((quad)     ^ (l15 & 7)) * 8;
  const int sw1 = ((quad + 4) ^ (l15 & 7)) * 8;

  const u16* qp = q  + (size_t)bh * 131072;
  const u16* kp = k  + (size_t)bh * 131072;
  const u16* vp = vt + (size_t)bh * 131072;

  // each wave owns 16 q-rows: qt*64 + w*16 + l15
  bf16x8 qf[2];
#pragma unroll
  for (int ks = 0; ks < 2; ks++)
    qf[ks] = *(const bf16x8*)(qp + (size_t)(qt * 64 + w * 16 + l15) * 64 + ks * 32 + quad * 8);

  f32x4 l_acc = {};
  f32x4 o[4] = {};

  bf16x8 ones;
  {
    short one = (short)0x3F80;
    ones = (bf16x8){one, one, one, one, one, one, one, one};
  }

  u16* Pw = &P_lds[w * 2 * 16 * 72];

#define S_PHASE(KB, PB)                                                        \
  do {                                                                         \
    _Pragma("unroll")                                                          \
    for (int jt = 0; jt < 4; jt++) {                                           \
      bf16x8 kf0 = *(const bf16x8*)&(KB)[(jt * 16 + l15) * 64 + sw0];          \
      bf16x8 kf1 = *(const bf16x8*)&(KB)[(jt * 16 + l15) * 64 + sw1];          \
      f32x4 s = {0.f, 0.f, 0.f, 0.f};                                          \
      s = MFMA16(kf0, qf[0], s);                                               \
      s = MFMA16(kf1, qf[1], s);                                               \
      u32 pb[4];                                                               \
      _Pragma("unroll")                                                        \
      for (int r = 0; r < 4; r++) pb[r] = __float_as_uint(EXP2(s[r]));         \
      uint2 pk;                                                                \
      pk.x = __builtin_amdgcn_perm(pb[1], pb[0], 0x07060302u);                 \
      pk.y = __builtin_amdgcn_perm(pb[3], pb[2], 0x07060302u);                 \
      *(uint2*)&(PB)[l15 * 72 + jt * 16 + quad * 4] = pk;                      \
    }                                                                          \
  } while (0)

#define PV_PHASE(VIT, PB)                                                      \
  do {                                                                         \
    bf16x8 vf[2][4];                                                           \
    _Pragma("unroll")                                                          \
    for (int dt = 0; dt < 4; dt++)                                             \
      vf[0][dt] = *(const bf16x8*)((VIT) + (dt * 16 + l15) * 32 + quad * 8);   \
    _Pragma("unroll")                                                          \
    for (int dt = 0; dt < 4; dt++)                                             \
      vf[1][dt] = *(const bf16x8*)((VIT) + 2048 + (dt * 16 + l15) * 32 + quad * 8); \
    __builtin_amdgcn_s_setprio(1);                                             \
    _Pragma("unroll")                                                          \
    for (int ks = 0; ks < 2; ks++) {                                           \
      bf16x8 pf = *(const bf16x8*)&(PB)[l15 * 72 + ks * 32 + quad * 8];        \
      l_acc = MFMA16(pf, ones, l_acc);                                         \
      _Pragma("unroll")                                                        \
      for (int dt = 0; dt < 4; dt++)                                           \
        o[dt] = MFMA16(pf, vf[ks][dt], o[dt]);                                 \
    }                                                                          \
    __builtin_amdgcn_s_setprio(0);                                             \
  } while (0)

  // prologue: stage K0,K1; compute S(0)
  stage_sw64(kp, K_lds[0], tid);
  stage_sw64(kp + 4096, K_lds[1], tid);
  __syncthreads();
  S_PHASE(K_lds[0], Pw);

  for (int it = 0; it < 31; it++) {
    __syncthreads();   // all waves done S(it) reads of K_lds[it&1]; K[it+1] landed
    if (it < 30) stage_sw64(kp + (size_t)(it + 2) * 4096, K_lds[it & 1], tid);
    u16* Pc = Pw + (it & 1) * 16 * 72;        // P(it), written last body
    u16* Pn = Pw + ((it + 1) & 1) * 16 * 72;  // P(it+1), written now
    S_PHASE(K_lds[(it + 1) & 1], Pn);
    PV_PHASE(vp + (it) * 4096, Pc);
  }
  PV_PHASE(vp + 31 * 4096, Pw + (31 & 1) * 16 * 72);

#undef S_PHASE
#undef PV_PHASE

  // epilogue: normalize, transpose via per-wave LDS, write yhi/ylo planes
  const int b = bh >> 3, h = bh & 7;
  u32* Tw = (u32*)Pw;
#pragma unroll
  for (int r = 0; r < 4; r++) {
    float inv = 1.f / l_acc[r];
#pragma unroll
    for (int dt = 0; dt < 4; dt++) {
      float val = o[dt][r] * inv;
      u16 hi = f2bf(val);
      u16 lo = f2bf(val - bf2f(hi));
      Tw[(quad * 4 + r) * 68 + dt * 16 + l15] = (u32)hi | ((u32)lo << 16);
    }
  }
  {
    int t = qt * 64 + w * 16 + l15;
    size_t rowb = (size_t)(b * 2048 + t) * 512 + h * 64 + quad * 16;
    uint4 g0 = *(uint4*)&Tw[l15 * 68 + quad * 16 + 0];
    uint4 g1 = *(uint4*)&Tw[l15 * 68 + quad * 16 + 4];
    uint4 g2 = *(uint4*)&Tw[l15 * 68 + quad * 16 + 8];
    uint4 g3 = *(uint4*)&Tw[l15 * 68 + quad * 16 + 12];
    uint4 hi4, lo4;
    hi4.x = __builtin_amdgcn_perm(g0.y, g0.x, 0x05040100u);
    hi4.y = __builtin_amdgcn_perm(g0.w, g0.z, 0x05040100u);
    hi4.z = __builtin_amdgcn_perm(g1.y, g1.x, 0x05040100u);
    hi4.w = __builtin_amdgcn_perm(g1.w, g1.z, 0x05040100u);
    lo4.x = __builtin_amdgcn_perm(g0.y, g0.x, 0x07060302u);
    lo4.y = __builtin_amdgcn_perm(g0.w, g0.z, 0x07060302u);
    lo4.z = __builtin_amdgcn_perm(g1.y, g1.x, 0x07060302u);
    lo4.w = __builtin_amdgcn_perm(g1.w, g1.z, 0x07060302u);
    *(uint4*)&yb[rowb] = hi4;
    *(uint4*)&yb[(size_t)4 * 2048 * 512 + rowb] = lo4;
    hi4.x = __builtin_amdgcn_perm(g2.y, g2.x, 0x05040100u);
    hi4.y = __builtin_amdgcn_perm(g2.w, g2.z, 0x05040100u);
    hi4.z = __builtin_amdgcn_perm(g3.y, g3.x, 0x05040100u);
    hi4.w = __builtin_amdgcn_perm(g3.w, g3.z, 0x05040100u);
    lo4.x = __builtin_amdgcn_perm(g2.y, g2.x, 0x07060302u);
    lo4.y = __builtin_amdgcn_perm(g2.w, g2.z, 0x07060302u);
    lo4.z = __builtin_amdgcn_perm(g3.y, g3.x, 0x07060302u);
    lo4.w = __builtin_amdgcn_perm(g3.w, g3.z, 0x07060302u);
    *(uint4*)&yb[rowb + 8] = hi4;
    *(uint4*)&yb[(size_t)4 * 2048 * 512 + rowb + 8] = lo4;
  }
}

// ---------------- output projection (128x64 tile, m97 structure) ---------
// 512 blocks, 2/CU. LDS 48 KB (Ah/Al 128x64 + Bh/Bl 64x64), global_load_lds
// staging, 2 barriers/K-step, 4x2 frag acc per wave, hi/lo 3-MFMA per frag.
__global__ __launch_bounds__(256) void gemm_out(const u16* __restrict__ yhi,
                                                const u16* __restrict__ ylo,
                                                const u16* __restrict__ whi,
                                                const u16* __restrict__ wlo,
                                                const float* __restrict__ b_out,
                                                float* __restrict__ out) {
  __shared__ u16 Ah[128 * 64];
  __shared__ u16 Al[128 * 64];
  __shared__ u16 Bh[64 * 64];
  __shared__ u16 Bl[64 * 64];
  const int bid = blockIdx.x;
  const int xcd = bid & 7, rr = bid >> 3;       // rr in [0,64)
  const int m0 = (xcd * 8 + (rr & 7)) * 128;    // 64 m-tiles
  const int n0 = (rr >> 3) * 64;                // 8 n-tiles
  const int tid  = threadIdx.x;
  const int lane = tid & 63, w = tid >> 6;
  const int wm = w >> 1, wn = w & 1;
  const int quad = lane >> 4, l15 = lane & 15;
  const int sw0 = ((quad)     ^ (l15 & 7)) * 8;
  const int sw1 = ((quad + 4) ^ (l15 & 7)) * 8;

  f32x4 acc[4][2] = {};

  for (int kt = 0; kt < 8; kt++) {
    const int k0 = kt * 64;
    stage_ld512<128>(yhi + (size_t)m0 * 512 + k0, Ah, tid);
    stage_ld512<128>(ylo + (size_t)m0 * 512 + k0, Al, tid);
    stage_ld512<64>(whi + (size_t)n0 * 512 + k0, Bh, tid);
    stage_ld512<64>(wlo + (size_t)n0 * 512 + k0, Bl, tid);
    __syncthreads();
#pragma unroll
    for (int ks = 0; ks < 2; ks++) {
      const int sw = ks ? sw1 : sw0;
      bf16x8 afh[4], afl[4], bfh[2], bfl[2];
#pragma unroll
      for (int ri = 0; ri < 4; ri++) {
        afh[ri] = *(const bf16x8*)&Ah[(wm * 64 + ri * 16 + l15) * 64 + sw];
        afl[ri] = *(const bf16x8*)&Al[(wm * 64 + ri * 16 + l15) * 64 + sw];
      }
#pragma unroll
      for (int ci = 0; ci < 2; ci++) {
        bfh[ci] = *(const bf16x8*)&Bh[(wn * 32 + ci * 16 + l15) * 64 + sw];
        bfl[ci] = *(const bf16x8*)&Bl[(wn * 32 + ci * 16 + l15) * 64 + sw];
      }
#pragma unroll
      for (int ri = 0; ri < 4; ri++)
#pragma unroll
        for (int ci = 0; ci < 2; ci++) {
          acc[ri][ci] = MFMA16(afh[ri], bfh[ci], acc[ri][ci]);
          acc[ri][ci] = MFMA16(afh[ri], bfl[ci], acc[ri][ci]);
          acc[ri][ci] = MFMA16(afl[ri], bfh[ci], acc[ri][ci]);
        }
    }
    __syncthreads();
  }

#pragma unroll
  for (int ri = 0; ri < 4; ri++) {
#pragma unroll
    for (int ci = 0; ci < 2; ci++) {
      int n = n0 + wn * 32 + ci * 16 + l15;
      float bias = b_out[n];
#pragma unroll
      for (int r = 0; r < 4; r++) {
        int m = m0 + wm * 64 + ri * 16 + quad * 4 + r;
        out[(size_t)m * 512 + n] = acc[ri][ci][r] + bias;
      }
    }
  }
}

// ---------------- launch ----------------
extern "C" void kernel_launch(void* const* d_in, const int* in_sizes, int n_in,
                              void* d_out, int out_size, void* d_ws, size_t ws_size,
                              hipStream_t stream) {
  const float* x      = (const float*)d_in[0];
  const float* W_attn = (const float*)d_in[1];
  const float* b_attn = (const float*)d_in[2];
  const float* W_out  = (const float*)d_in[3];
  const float* b_out  = (const float*)d_in[4];
  float* out = (float*)d_out;

  char* ws = (char*)d_ws;
  u16* xb   = (u16*)(ws + 0);                 //  8 MB  [8192][512]
  u16* wta  = (u16*)(ws + 8388608);           //  1.5MB [1536][512]
  u16* wtoh = (u16*)(ws + 9961472);           //  0.5MB [512][512]
  u16* wtol = (u16*)(ws + 10485760);          //  0.5MB
  u16* qb   = (u16*)(ws + 11010048);          //  8 MB  [bh][t][64] (pre-scaled)
  u16* kb   = (u16*)(ws + 19398656);          //  8 MB  [bh][t][64]
  u16* vtb  = (u16*)(ws + 27787264);          //  8 MB  V' frag-packed
  u16* yhi  = (u16*)(ws + 36175872);          //  8 MB  [B,T,C] (+8 MB lo plane)

  prep_kernel<<<4352, 256, 0, stream>>>(x, xb, W_attn, wta, W_out, wtoh, wtol);
  gemm_qkv<<<768, 256, 0, stream>>>(xb, wta, b_attn, qb, kb, vtb);
  flash_attn<<<dim3(16, 32), 256, 0, stream>>>(qb, kb, vtb, yhi, 0);
  flash_attn<<<dim3(16, 32), 256, 0, stream>>>(qb, kb, vtb, yhi, 32);
  gemm_out<<<512, 256, 0, stream>>>(yhi, yhi + (size_t)4 * 2048 * 512, wtoh, wtol, b_out, out);
}

// Round 6
// 191.450 us; speedup vs baseline: 1.1084x; 1.1084x over previous
//
#include <hip/hip_runtime.h>

typedef __attribute__((ext_vector_type(8))) short bf16x8;
typedef __attribute__((ext_vector_type(4))) float f32x4;
typedef unsigned short u16;
typedef unsigned int u32;

#define MFMA16(A, B, C) __builtin_amdgcn_mfma_f32_16x16x32_bf16((A), (B), (C), 0, 0, 0)

#if __has_builtin(__builtin_amdgcn_exp2f)
#define EXP2(x) __builtin_amdgcn_exp2f(x)
#else
#define EXP2(x) exp2f(x)
#endif

typedef __attribute__((address_space(3))) unsigned int lds_u32;
typedef const __attribute__((address_space(1))) unsigned int glb_u32;

__device__ __forceinline__ u16 f2bf(float f) {
  union { float f; unsigned u; } x; x.f = f;
  unsigned r = (x.u + 0x7fffu + ((x.u >> 16) & 1u)) >> 16;
  return (u16)r;
}
__device__ __forceinline__ float bf2f(u16 h) {
  union { float f; unsigned u; } x; x.u = ((unsigned)h) << 16;
  return x.f;
}

// stage a 64x64 bf16 tile (ld=64) into contiguous LDS via global_load_lds,
// XOR-swizzled: LDS slot (row, c) holds global chunk c^(row&7).
__device__ __forceinline__ void stage_sw64(const u16* src, u16* lds, int tid) {
#pragma unroll
  for (int i = 0; i < 2; i++) {
    int vv = tid + i * 256;
    int row = vv >> 3, c = vv & 7;
    const u16* gp = src + (size_t)row * 64 + (size_t)(c ^ (row & 7)) * 8;
    __builtin_amdgcn_global_load_lds((glb_u32*)gp,
        (lds_u32*)(lds + (size_t)(i * 256 + (tid & 192)) * 8), 16, 0, 0);
  }
}

// stage ROWS x 64 bf16 tile from a row-major [*][512] matrix (ld=512) into
// contiguous LDS, same XOR swizzle. ROWS in {64, 128}.
template <int ROWS>
__device__ __forceinline__ void stage_ld512(const u16* src, u16* lds, int tid) {
#pragma unroll
  for (int i = 0; i < ROWS / 32; i++) {
    int vv = tid + i * 256;
    int row = vv >> 3, c = vv & 7;
    const u16* gp = src + (size_t)row * 512 + (size_t)(c ^ (row & 7)) * 8;
    __builtin_amdgcn_global_load_lds((glb_u32*)gp,
        (lds_u32*)(lds + (size_t)(i * 256 + (tid & 192)) * 8), 16, 0, 0);
  }
}

// ---------------- fused prep kernel ----------------
// blocks [0,4096): cast x -> xb (bf16)
// blocks [4096,4288): W_attn [512][1536] -> wta [1536][512] bf16 (64x64 tiles)
// blocks [4288,4352): W_out [512][512] -> whi/wlo [512][512] bf16 (hi/lo split)
__global__ __launch_bounds__(256) void prep_kernel(const float* __restrict__ x,
                                                   u16* __restrict__ xb,
                                                   const float* __restrict__ Wa,
                                                   u16* __restrict__ wta,
                                                   const float* __restrict__ Wo,
                                                   u16* __restrict__ whi,
                                                   u16* __restrict__ wlo) {
  __shared__ u16 Th[64][72];
  __shared__ u16 Tl[64][72];
  const int bid = blockIdx.x;
  const int tid = threadIdx.x;

  if (bid < 4096) {
    int i = bid * 256 + tid;
    float4 v = ((const float4*)x)[i];
    ushort4 o;
    o.x = f2bf(v.x); o.y = f2bf(v.y); o.z = f2bf(v.z); o.w = f2bf(v.w);
    ((ushort4*)xb)[i] = o;
    return;
  }

  if (bid < 4288) {
    const int t = bid - 4096;
    const int n0 = (t % 24) * 64;
    const int k0 = (t / 24) * 64;
    const int r = tid >> 4, c4 = (tid & 15) * 4;
#pragma unroll
    for (int i = 0; i < 4; i++) {
      int row = r + i * 16;
      float4 v = *(const float4*)&Wa[(size_t)(k0 + row) * 1536 + n0 + c4];
      Th[c4 + 0][row] = f2bf(v.x);
      Th[c4 + 1][row] = f2bf(v.y);
      Th[c4 + 2][row] = f2bf(v.z);
      Th[c4 + 3][row] = f2bf(v.w);
    }
    __syncthreads();
    const int row = tid >> 2, c16 = (tid & 3) * 16;
    *(uint4*)&wta[(size_t)(n0 + row) * 512 + k0 + c16]     = *(uint4*)&Th[row][c16];
    *(uint4*)&wta[(size_t)(n0 + row) * 512 + k0 + c16 + 8] = *(uint4*)&Th[row][c16 + 8];
    return;
  }

  {
    const int t = bid - 4288;
    const int n0 = (t & 7) * 64;
    const int k0 = (t >> 3) * 64;
    const int r = tid >> 4, c4 = (tid & 15) * 4;
#pragma unroll
    for (int i = 0; i < 4; i++) {
      int row = r + i * 16;
      float4 v = *(const float4*)&Wo[(size_t)(k0 + row) * 512 + n0 + c4];
      float vv[4] = {v.x, v.y, v.z, v.w};
#pragma unroll
      for (int jj = 0; jj < 4; jj++) {
        u16 hi = f2bf(vv[jj]);
        Th[c4 + jj][row] = hi;
        Tl[c4 + jj][row] = f2bf(vv[jj] - bf2f(hi));
      }
    }
    __syncthreads();
    const int row = tid >> 2, c16 = (tid & 3) * 16;
    *(uint4*)&whi[(size_t)(n0 + row) * 512 + k0 + c16]     = *(uint4*)&Th[row][c16];
    *(uint4*)&whi[(size_t)(n0 + row) * 512 + k0 + c16 + 8] = *(uint4*)&Th[row][c16 + 8];
    *(uint4*)&wlo[(size_t)(n0 + row) * 512 + k0 + c16]     = *(uint4*)&Tl[row][c16];
    *(uint4*)&wlo[(size_t)(n0 + row) * 512 + k0 + c16 + 8] = *(uint4*)&Tl[row][c16 + 8];
  }
}

// ---------------- QKV GEMM (128x128 tile, 2-phase LDS dbuf) --------------
// T3-minimum pipeline: stage(kt+1) issued BEFORE compute(kt); loads land
// during compute; ONE barrier per K-step (its vmcnt0 drain arrives after
// the latency is already hidden). LDS 64 KB -> 2 blocks/CU (ILP replaces
// the lost TLP).
__global__ __launch_bounds__(256) void gemm_qkv(const u16* __restrict__ xb,
                                                const u16* __restrict__ wta,
                                                const float* __restrict__ b_attn,
                                                u16* __restrict__ q,
                                                u16* __restrict__ kk,
                                                u16* __restrict__ v) {
  __shared__ u16 A_lds[2][128 * 64];
  __shared__ u16 B_lds[2][128 * 64];
  const int bid = blockIdx.x;
  const int xcd = bid & 7, rr = bid >> 3;       // rr in [0,96)
  const int m0 = (xcd * 8 + (rr & 7)) * 128;    // 64 m-tiles
  const int n0 = (rr >> 3) * 128;               // 12 n-tiles
  const int tid  = threadIdx.x;
  const int lane = tid & 63, w = tid >> 6;
  const int wm = w >> 1, wn = w & 1;
  const int quad = lane >> 4, l15 = lane & 15;
  const int sw0 = ((quad)     ^ (l15 & 7)) * 8;
  const int sw1 = ((quad + 4) ^ (l15 & 7)) * 8;

  f32x4 acc[4][4] = {};

  stage_ld512<128>(xb  + (size_t)m0 * 512, A_lds[0], tid);
  stage_ld512<128>(wta + (size_t)n0 * 512, B_lds[0], tid);
  __syncthreads();

  for (int kt = 0; kt < 8; kt++) {
    const u16* Ab = A_lds[kt & 1];
    const u16* Bb = B_lds[kt & 1];
    if (kt < 7) {
      stage_ld512<128>(xb  + (size_t)m0 * 512 + (kt + 1) * 64, A_lds[(kt + 1) & 1], tid);
      stage_ld512<128>(wta + (size_t)n0 * 512 + (kt + 1) * 64, B_lds[(kt + 1) & 1], tid);
    }
#pragma unroll
    for (int ks = 0; ks < 2; ks++) {
      const int sw = ks ? sw1 : sw0;
      bf16x8 af[4], bf[4];
#pragma unroll
      for (int ri = 0; ri < 4; ri++)
        af[ri] = *(const bf16x8*)&Ab[(wm * 64 + ri * 16 + l15) * 64 + sw];
#pragma unroll
      for (int ci = 0; ci < 4; ci++)
        bf[ci] = *(const bf16x8*)&Bb[(wn * 64 + ci * 16 + l15) * 64 + sw];
#pragma unroll
      for (int ri = 0; ri < 4; ri++)
#pragma unroll
        for (int ci = 0; ci < 4; ci++)
          acc[ri][ci] = MFMA16(af[ri], bf[ci], acc[ri][ci]);
    }
    __syncthreads();
  }

  const float QS = 0.18033688011112043f;  // 0.125 * log2(e)
#pragma unroll
  for (int ri = 0; ri < 4; ri++) {
#pragma unroll
    for (int ci = 0; ci < 4; ci++) {
      int n = n0 + wn * 64 + ci * 16 + l15;
      float bias = b_attn[n];
      int chunk = n >> 9;
      int c = n & 511;
      int h = c >> 6, d = c & 63;
      int m_base = m0 + wm * 64 + ri * 16 + quad * 4;
      int b = m_base >> 11, t0 = m_base & 2047;
      int bh = b * 8 + h;
      if (chunk == 0) {
#pragma unroll
        for (int r = 0; r < 4; r++)
          q[(size_t)(bh * 2048 + t0 + r) * 64 + d] = f2bf((acc[ri][ci][r] + bias) * QS);
      } else if (chunk == 1) {
#pragma unroll
        for (int r = 0; r < 4; r++)
          kk[(size_t)(bh * 2048 + t0 + r) * 64 + d] = f2bf(acc[ri][ci][r] + bias);
      } else {
        int it = t0 >> 7, ks2 = (t0 >> 5) & 3, qd = (t0 >> 3) & 3, jj = t0 & 7;
        ushort4 pk;
        pk.x = f2bf(acc[ri][ci][0] + bias);
        pk.y = f2bf(acc[ri][ci][1] + bias);
        pk.z = f2bf(acc[ri][ci][2] + bias);
        pk.w = f2bf(acc[ri][ci][3] + bias);
        size_t idx = ((((size_t)bh * 16 + it) * 4 + ks2) * 64 + d) * 32 + qd * 8 + jj;
        *(ushort4*)&v[idx] = pk;
      }
    }
  }
}

// ---------------- flash attention (r1/r3 structure, single launch) -------
// Reverted r5's half-grid split: 2 blocks/CU cost 52.9x2 vs 81.4 single.
__global__ __launch_bounds__(256, 4) void flash_attn(const u16* __restrict__ q,
                                                     const u16* __restrict__ k,
                                                     const u16* __restrict__ vt,
                                                     u16* __restrict__ yb) {
  __shared__ u16 K_lds[2][64 * 64];
  __shared__ u16 P_lds[4 * 2 * 16 * 72];  // per-wave 2 x [16 q][64 +pad]

  const int flat = blockIdx.y * 16 + blockIdx.x;
  const int bh = (flat & 7) * 4 + ((flat >> 3) & 3);  // 4 bh per XCD -> K/V L2-resident
  const int qt = flat >> 5;                           // 0..31, 64 q-rows each

  const int tid  = threadIdx.x;
  const int lane = tid & 63, w = tid >> 6;
  const int quad = lane >> 4, l15 = lane & 15;
  const int sw0 = ((quad)     ^ (l15 & 7)) * 8;
  const int sw1 = ((quad + 4) ^ (l15 & 7)) * 8;

  const u16* qp = q  + (size_t)bh * 131072;
  const u16* kp = k  + (size_t)bh * 131072;
  const u16* vp = vt + (size_t)bh * 131072;

  bf16x8 qf[2];
#pragma unroll
  for (int ks = 0; ks < 2; ks++)
    qf[ks] = *(const bf16x8*)(qp + (size_t)(qt * 64 + w * 16 + l15) * 64 + ks * 32 + quad * 8);

  f32x4 l_acc = {};
  f32x4 o[4] = {};

  bf16x8 ones;
  {
    short one = (short)0x3F80;
    ones = (bf16x8){one, one, one, one, one, one, one, one};
  }

  u16* Pw = &P_lds[w * 2 * 16 * 72];

#define S_PHASE(KB, PB)                                                        \
  do {                                                                         \
    _Pragma("unroll")                                                          \
    for (int jt = 0; jt < 4; jt++) {                                           \
      bf16x8 kf0 = *(const bf16x8*)&(KB)[(jt * 16 + l15) * 64 + sw0];          \
      bf16x8 kf1 = *(const bf16x8*)&(KB)[(jt * 16 + l15) * 64 + sw1];          \
      f32x4 s = {0.f, 0.f, 0.f, 0.f};                                          \
      s = MFMA16(kf0, qf[0], s);                                               \
      s = MFMA16(kf1, qf[1], s);                                               \
      u32 pb[4];                                                               \
      _Pragma("unroll")                                                        \
      for (int r = 0; r < 4; r++) pb[r] = __float_as_uint(EXP2(s[r]));         \
      uint2 pk;                                                                \
      pk.x = __builtin_amdgcn_perm(pb[1], pb[0], 0x07060302u);                 \
      pk.y = __builtin_amdgcn_perm(pb[3], pb[2], 0x07060302u);                 \
      *(uint2*)&(PB)[l15 * 72 + jt * 16 + quad * 4] = pk;                      \
    }                                                                          \
  } while (0)

#define PV_PHASE(VIT, PB)                                                      \
  do {                                                                         \
    bf16x8 vf[2][4];                                                           \
    _Pragma("unroll")                                                          \
    for (int dt = 0; dt < 4; dt++)                                             \
      vf[0][dt] = *(const bf16x8*)((VIT) + (dt * 16 + l15) * 32 + quad * 8);   \
    _Pragma("unroll")                                                          \
    for (int dt = 0; dt < 4; dt++)                                             \
      vf[1][dt] = *(const bf16x8*)((VIT) + 2048 + (dt * 16 + l15) * 32 + quad * 8); \
    __builtin_amdgcn_s_setprio(1);                                             \
    _Pragma("unroll")                                                          \
    for (int ks = 0; ks < 2; ks++) {                                           \
      bf16x8 pf = *(const bf16x8*)&(PB)[l15 * 72 + ks * 32 + quad * 8];        \
      l_acc = MFMA16(pf, ones, l_acc);                                         \
      _Pragma("unroll")                                                        \
      for (int dt = 0; dt < 4; dt++)                                           \
        o[dt] = MFMA16(pf, vf[ks][dt], o[dt]);                                 \
    }                                                                          \
    __builtin_amdgcn_s_setprio(0);                                             \
  } while (0)

  stage_sw64(kp, K_lds[0], tid);
  stage_sw64(kp + 4096, K_lds[1], tid);
  __syncthreads();
  S_PHASE(K_lds[0], Pw);

  for (int it = 0; it < 31; it++) {
    __syncthreads();
    if (it < 30) stage_sw64(kp + (size_t)(it + 2) * 4096, K_lds[it & 1], tid);
    u16* Pc = Pw + (it & 1) * 16 * 72;
    u16* Pn = Pw + ((it + 1) & 1) * 16 * 72;
    S_PHASE(K_lds[(it + 1) & 1], Pn);
    PV_PHASE(vp + (it) * 4096, Pc);
  }
  PV_PHASE(vp + 31 * 4096, Pw + (31 & 1) * 16 * 72);

#undef S_PHASE
#undef PV_PHASE

  const int b = bh >> 3, h = bh & 7;
  u32* Tw = (u32*)Pw;
#pragma unroll
  for (int r = 0; r < 4; r++) {
    float inv = 1.f / l_acc[r];
#pragma unroll
    for (int dt = 0; dt < 4; dt++) {
      float val = o[dt][r] * inv;
      u16 hi = f2bf(val);
      u16 lo = f2bf(val - bf2f(hi));
      Tw[(quad * 4 + r) * 68 + dt * 16 + l15] = (u32)hi | ((u32)lo << 16);
    }
  }
  {
    int t = qt * 64 + w * 16 + l15;
    size_t rowb = (size_t)(b * 2048 + t) * 512 + h * 64 + quad * 16;
    uint4 g0 = *(uint4*)&Tw[l15 * 68 + quad * 16 + 0];
    uint4 g1 = *(uint4*)&Tw[l15 * 68 + quad * 16 + 4];
    uint4 g2 = *(uint4*)&Tw[l15 * 68 + quad * 16 + 8];
    uint4 g3 = *(uint4*)&Tw[l15 * 68 + quad * 16 + 12];
    uint4 hi4, lo4;
    hi4.x = __builtin_amdgcn_perm(g0.y, g0.x, 0x05040100u);
    hi4.y = __builtin_amdgcn_perm(g0.w, g0.z, 0x05040100u);
    hi4.z = __builtin_amdgcn_perm(g1.y, g1.x, 0x05040100u);
    hi4.w = __builtin_amdgcn_perm(g1.w, g1.z, 0x05040100u);
    lo4.x = __builtin_amdgcn_perm(g0.y, g0.x, 0x07060302u);
    lo4.y = __builtin_amdgcn_perm(g0.w, g0.z, 0x07060302u);
    lo4.z = __builtin_amdgcn_perm(g1.y, g1.x, 0x07060302u);
    lo4.w = __builtin_amdgcn_perm(g1.w, g1.z, 0x07060302u);
    *(uint4*)&yb[rowb] = hi4;
    *(uint4*)&yb[(size_t)4 * 2048 * 512 + rowb] = lo4;
    hi4.x = __builtin_amdgcn_perm(g2.y, g2.x, 0x05040100u);
    hi4.y = __builtin_amdgcn_perm(g2.w, g2.z, 0x05040100u);
    hi4.z = __builtin_amdgcn_perm(g3.y, g3.x, 0x05040100u);
    hi4.w = __builtin_amdgcn_perm(g3.w, g3.z, 0x05040100u);
    lo4.x = __builtin_amdgcn_perm(g2.y, g2.x, 0x07060302u);
    lo4.y = __builtin_amdgcn_perm(g2.w, g2.z, 0x07060302u);
    lo4.z = __builtin_amdgcn_perm(g3.y, g3.x, 0x07060302u);
    lo4.w = __builtin_amdgcn_perm(g3.w, g3.z, 0x07060302u);
    *(uint4*)&yb[rowb + 8] = hi4;
    *(uint4*)&yb[(size_t)4 * 2048 * 512 + rowb + 8] = lo4;
  }
}

// ---------------- output projection (64x64 tile, 2-phase dbuf) -----------
// 1024 blocks (2 clean rounds at 2/CU), 4 tiles (Ah/Al/Bh/Bl) x 8KB dbuf =
// 64 KB LDS. Same T3-minimum pipeline as gemm_qkv: stage next K-step before
// compute, one barrier per step.
__global__ __launch_bounds__(256) void gemm_out(const u16* __restrict__ yhi,
                                                const u16* __restrict__ ylo,
                                                const u16* __restrict__ whi,
                                                const u16* __restrict__ wlo,
                                                const float* __restrict__ b_out,
                                                float* __restrict__ out) {
  __shared__ u16 Ah[2][64 * 64];
  __shared__ u16 Al[2][64 * 64];
  __shared__ u16 Bh[2][64 * 64];
  __shared__ u16 Bl[2][64 * 64];
  const int bid = blockIdx.x;
  const int xcd = bid & 7, rr = bid >> 3;       // rr in [0,128)
  const int m0 = (xcd * 16 + (rr & 15)) * 64;   // 128 m-tiles
  const int n0 = (rr >> 4) * 64;                // 8 n-tiles
  const int tid  = threadIdx.x;
  const int lane = tid & 63, w = tid >> 6;
  const int wm = w >> 1, wn = w & 1;
  const int quad = lane >> 4, l15 = lane & 15;
  const int sw0 = ((quad)     ^ (l15 & 7)) * 8;
  const int sw1 = ((quad + 4) ^ (l15 & 7)) * 8;

  f32x4 acc[2][2] = {};

  stage_ld512<64>(yhi + (size_t)m0 * 512, Ah[0], tid);
  stage_ld512<64>(ylo + (size_t)m0 * 512, Al[0], tid);
  stage_ld512<64>(whi + (size_t)n0 * 512, Bh[0], tid);
  stage_ld512<64>(wlo + (size_t)n0 * 512, Bl[0], tid);
  __syncthreads();

  for (int kt = 0; kt < 8; kt++) {
    const int cur = kt & 1;
    if (kt < 7) {
      const int nxt = cur ^ 1, k0 = (kt + 1) * 64;
      stage_ld512<64>(yhi + (size_t)m0 * 512 + k0, Ah[nxt], tid);
      stage_ld512<64>(ylo + (size_t)m0 * 512 + k0, Al[nxt], tid);
      stage_ld512<64>(whi + (size_t)n0 * 512 + k0, Bh[nxt], tid);
      stage_ld512<64>(wlo + (size_t)n0 * 512 + k0, Bl[nxt], tid);
    }
#pragma unroll
    for (int ks = 0; ks < 2; ks++) {
      const int sw = ks ? sw1 : sw0;
      bf16x8 afh[2], afl[2], bfh[2], bfl[2];
#pragma unroll
      for (int ri = 0; ri < 2; ri++) {
        afh[ri] = *(const bf16x8*)&Ah[cur][(wm * 32 + ri * 16 + l15) * 64 + sw];
        afl[ri] = *(const bf16x8*)&Al[cur][(wm * 32 + ri * 16 + l15) * 64 + sw];
      }
#pragma unroll
      for (int ci = 0; ci < 2; ci++) {
        bfh[ci] = *(const bf16x8*)&Bh[cur][(wn * 32 + ci * 16 + l15) * 64 + sw];
        bfl[ci] = *(const bf16x8*)&Bl[cur][(wn * 32 + ci * 16 + l15) * 64 + sw];
      }
#pragma unroll
      for (int ri = 0; ri < 2; ri++)
#pragma unroll
        for (int ci = 0; ci < 2; ci++) {
          acc[ri][ci] = MFMA16(afh[ri], bfh[ci], acc[ri][ci]);
          acc[ri][ci] = MFMA16(afh[ri], bfl[ci], acc[ri][ci]);
          acc[ri][ci] = MFMA16(afl[ri], bfh[ci], acc[ri][ci]);
        }
    }
    __syncthreads();
  }

#pragma unroll
  for (int ri = 0; ri < 2; ri++) {
#pragma unroll
    for (int ci = 0; ci < 2; ci++) {
      int n = n0 + wn * 32 + ci * 16 + l15;
      float bias = b_out[n];
#pragma unroll
      for (int r = 0; r < 4; r++) {
        int m = m0 + wm * 32 + ri * 16 + quad * 4 + r;
        out[(size_t)m * 512 + n] = acc[ri][ci][r] + bias;
      }
    }
  }
}

// ---------------- launch ----------------
extern "C" void kernel_launch(void* const* d_in, const int* in_sizes, int n_in,
                              void* d_out, int out_size, void* d_ws, size_t ws_size,
                              hipStream_t stream) {
  const float* x      = (const float*)d_in[0];
  const float* W_attn = (const float*)d_in[1];
  const float* b_attn = (const float*)d_in[2];
  const float* W_out  = (const float*)d_in[3];
  const float* b_out  = (const float*)d_in[4];
  float* out = (float*)d_out;

  char* ws = (char*)d_ws;
  u16* xb   = (u16*)(ws + 0);                 //  8 MB  [8192][512]
  u16* wta  = (u16*)(ws + 8388608);           //  1.5MB [1536][512]
  u16* wtoh = (u16*)(ws + 9961472);           //  0.5MB [512][512]
  u16* wtol = (u16*)(ws + 10485760);          //  0.5MB
  u16* qb   = (u16*)(ws + 11010048);          //  8 MB  [bh][t][64] (pre-scaled)
  u16* kb   = (u16*)(ws + 19398656);          //  8 MB  [bh][t][64]
  u16* vtb  = (u16*)(ws + 27787264);          //  8 MB  V' frag-packed
  u16* yhi  = (u16*)(ws + 36175872);          //  8 MB  [B,T,C] (+8 MB lo plane)

  prep_kernel<<<4352, 256, 0, stream>>>(x, xb, W_attn, wta, W_out, wtoh, wtol);
  gemm_qkv<<<768, 256, 0, stream>>>(xb, wta, b_attn, qb, kb, vtb);
  flash_attn<<<dim3(16, 64), 256, 0, stream>>>(qb, kb, vtb, yhi);
  gemm_out<<<1024, 256, 0, stream>>>(yhi, yhi + (size_t)4 * 2048 * 512, wtoh, wtol, b_out, out);
}